// Round 5
// baseline (487.024 us; speedup 1.0000x reference)
//
#include <hip/hip_runtime.h>
#include <math.h>

#define BN_EPS 1e-5
#define SIGMA 1.0f

// ============ conv1 partial: (8,128,64,64) -> fp32 partials, 3x3 s2 p1, fp64 acc ============
// grid 1024 = ocg(8) x isp(8: 16 ic) x b(8) x oht(2); block 128 = ow(32) x ohp(4)
// thread: 4 output rows x 8 oc over 16 ic -> 288 FMA per 36 weight-b64 (2x r1's ratio),
// kh-phase structure keeps live fp64 count low (VGPR<=128, 8 blocks/CU, 16 waves/CU).
// wave ic-stagger breaks the load-burst convoy (commutative fp64 reorder, ~1e-16).
__global__ __launch_bounds__(128, 4) void conv1_partial_kernel(
    const float* __restrict__ in, const float* __restrict__ w1,
    float* __restrict__ part)
{
    __shared__ double wlds[1152];   // [ic(16)][k(9)][j(8)] = 9.2 KB

    int bid = blockIdx.x;
    int oht = bid & 1;
    int b   = (bid >> 1) & 7;
    int isp = (bid >> 4) & 7;      // 16 ic per split
    int ocg = bid >> 7;            // stride 128 (%8==0): input-sharing siblings same XCD slot

    int tid = threadIdx.x;
    int ow  = tid & 31;
    int ohp = (tid >> 5) & 3;      // 0..3
    int oh0 = oht * 16 + ohp * 4;  // rows oh0..oh0+3
    int ih0 = 2 * oh0 - 1;
    int iw0 = 2 * ow - 1;

    for (int i = tid; i < 1152; i += 128) {
        int j  = i & 7;
        int t  = i >> 3;
        int k  = t % 9;
        int ic = t / 9;
        wlds[i] = (double)w1[((ocg * 8 + j) * 128 + isp * 16 + ic) * 9 + k];
    }
    __syncthreads();

    double acc[4][8];
    #pragma unroll
    for (int r = 0; r < 4; ++r)
        #pragma unroll
        for (int j = 0; j < 8; ++j) acc[r][j] = 0.0;

    // only the very first input row (ih0==-1) and first column (iw0==-1) can be OOB;
    // max ih = ih0+8 = 63, max iw = iw0+2 = 63 are always in range.
    bool row0ok = (ih0 >= 0);
    bool col0ok = (iw0 >= 0);

    const float* base0 = in + ((size_t)(b * 128 + isp * 16) * 64 + ih0) * 64 + iw0;

    int icoff = (tid >> 6) << 3;   // wave 0 starts at ic 0, wave 1 at ic 8

    for (int ii = 0; ii < 16; ++ii) {
        int ic = (ii + icoff) & 15;
        const float* bi = base0 + (size_t)ic * 4096;
        const double* wk = &wlds[ic * 72];

        #pragma unroll
        for (int kh = 0; kh < 3; ++kh) {
            // input rows for this kh: t = kh + 2r, r = 0..3  (t in 0..8)
            double xv[12];
            #pragma unroll
            for (int r = 0; r < 4; ++r) {
                int t = kh + 2 * r;
                bool rok = (t > 0) || row0ok;
                #pragma unroll
                for (int c = 0; c < 3; ++c) {
                    bool ok = rok && ((c > 0) || col0ok);
                    float f = ok ? bi[t * 64 + c] : 0.f;
                    xv[r * 3 + c] = (double)f;
                }
            }
            #pragma unroll
            for (int kw = 0; kw < 3; ++kw) {
                const double* wp = &wk[(kh * 3 + kw) * 8];
                double2 wa = *(const double2*)&wp[0];
                double2 wb2 = *(const double2*)&wp[2];
                double2 wc = *(const double2*)&wp[4];
                double2 wd = *(const double2*)&wp[6];
                #pragma unroll
                for (int r = 0; r < 4; ++r) {
                    double x = xv[r * 3 + kw];
                    acc[r][0] = fma(x, wa.x, acc[r][0]);
                    acc[r][1] = fma(x, wa.y, acc[r][1]);
                    acc[r][2] = fma(x, wb2.x, acc[r][2]);
                    acc[r][3] = fma(x, wb2.y, acc[r][3]);
                    acc[r][4] = fma(x, wc.x, acc[r][4]);
                    acc[r][5] = fma(x, wc.y, acc[r][5]);
                    acc[r][6] = fma(x, wd.x, acc[r][6]);
                    acc[r][7] = fma(x, wd.y, acc[r][7]);
                }
            }
        }
    }

    #pragma unroll
    for (int r = 0; r < 4; ++r)
        #pragma unroll
        for (int j = 0; j < 8; ++j) {
            int idx = ((b * 64 + ocg * 8 + j) * 32 + oh0 + r) * 32 + ow;
            part[(size_t)isp * 524288 + idx] = (float)acc[r][j];
        }
}

// ============ conv2 partial, FUSED with conv1-combine (sum 8 partials + BN1 + ReLU) =========
// grid 512 = isp(16: 4 ic) x b(8) x ocg(4); block 256 = full 16x16 spatial
// y1 values computed inline at identical fp64 op order -> bit-identical to separate combine
__global__ __launch_bounds__(256) void conv2_partial_kernel(
    const float* __restrict__ part1,
    const float* __restrict__ g1, const float* __restrict__ be1,
    const float* __restrict__ mn1, const float* __restrict__ vr1,
    const float* __restrict__ w,
    float* __restrict__ part)
{
    __shared__ float tin[4][33][36];
    __shared__ float twt[4][9][8];
    __shared__ double sinv[4], ssh[4];

    int bid = blockIdx.x;
    int ocg = bid & 3;
    int b   = (bid >> 2) & 7;
    int isp = bid >> 5;

    int tid = threadIdx.x;
    int ow  = tid & 15;
    int oh  = tid >> 4;

    if (tid < 4) {
        int ch = isp * 4 + tid;
        double inv = (double)g1[ch] / sqrt((double)vr1[ch] + BN_EPS);
        sinv[tid] = inv;
        ssh[tid]  = (double)be1[ch] - (double)mn1[ch] * inv;
    }
    __syncthreads();

    for (int lin = tid; lin < 4 * 33 * 34; lin += 256) {
        int c   = lin % 34;
        int t2  = lin / 34;
        int rr  = t2 % 33;
        int icc = t2 / 33;
        int ih  = rr - 1;
        int iw  = c - 1;
        float v = 0.f;
        if ((unsigned)ih < 32u && (unsigned)iw < 32u) {
            int ch  = isp * 4 + icc;
            int idx = ((b * 64 + ch) * 32 + ih) * 32 + iw;
            double s = 0.0;
            #pragma unroll
            for (int p = 0; p < 8; ++p) s += (double)part1[idx + p * 524288];
            double o = s * sinv[icc] + ssh[icc];
            v = fmaxf((float)o, 0.f);
        }
        tin[icc][rr][c] = v;
    }
    for (int i = tid; i < 288; i += 256) {
        int j   = i & 7;
        int k   = (i >> 3) % 9;
        int icc = i / 72;
        twt[icc][k][j] = w[(ocg * 8 + j) * 576 + (isp * 4 + icc) * 9 + k];
    }
    __syncthreads();

    double acc[8];
    #pragma unroll
    for (int j = 0; j < 8; ++j) acc[j] = 0.0;

    for (int icc = 0; icc < 4; ++icc) {
        double xv[9];
        #pragma unroll
        for (int kh = 0; kh < 3; ++kh)
            #pragma unroll
            for (int kw = 0; kw < 3; ++kw)
                xv[kh * 3 + kw] = (double)tin[icc][2 * oh + kh][2 * ow + kw];
        #pragma unroll
        for (int k = 0; k < 9; ++k) {
            float4 wa = *(const float4*)&twt[icc][k][0];
            float4 wb = *(const float4*)&twt[icc][k][4];
            acc[0] = fma(xv[k], (double)wa.x, acc[0]);
            acc[1] = fma(xv[k], (double)wa.y, acc[1]);
            acc[2] = fma(xv[k], (double)wa.z, acc[2]);
            acc[3] = fma(xv[k], (double)wa.w, acc[3]);
            acc[4] = fma(xv[k], (double)wb.x, acc[4]);
            acc[5] = fma(xv[k], (double)wb.y, acc[5]);
            acc[6] = fma(xv[k], (double)wb.z, acc[6]);
            acc[7] = fma(xv[k], (double)wb.w, acc[7]);
        }
    }
    int obase = ((b * 32 + ocg * 8) * 16 + oh) * 16 + ow;
    #pragma unroll
    for (int j = 0; j < 8; ++j)
        part[isp * 65536 + obase + j * 256] = (float)acc[j];
}

// ============ conv2 combine + BN + ReLU + spatial mean -> ybar[256] (y2 never stored) ======
__global__ __launch_bounds__(256) void conv2_combine_ybar_kernel(
    const float* __restrict__ part,
    const float* __restrict__ g, const float* __restrict__ be,
    const float* __restrict__ mn, const float* __restrict__ vr,
    double* __restrict__ ybar)
{
    __shared__ double sm[4];
    int j  = blockIdx.x;             // j = b*32 + oc
    int oc = j & 31;
    int t  = threadIdx.x;
    int idx = j * 256 + t;
    double s = 0.0;
    #pragma unroll
    for (int p = 0; p < 16; ++p) s += (double)part[idx + p * 65536];
    double inv = (double)g[oc] / sqrt((double)vr[oc] + BN_EPS);
    double o = s * inv + ((double)be[oc] - (double)mn[oc] * inv);
    double v = fmax(o, 0.0);
    #pragma unroll
    for (int off = 32; off > 0; off >>= 1) v += __shfl_down(v, off, 64);
    if ((t & 63) == 0) sm[t >> 6] = v;
    __syncthreads();
    if (t == 0) ybar[j] = (sm[0] + sm[1] + sm[2] + sm[3]) * (1.0 / 256.0);
}

// ============ centers: conv3(1x1)+BN folded with the spatial mean, fp64 ============
__global__ __launch_bounds__(64) void centers_kernel(
    const double* __restrict__ ybar, const float* __restrict__ w3,
    const float* __restrict__ g, const float* __restrict__ be,
    const float* __restrict__ mn, const float* __restrict__ vr,
    double* __restrict__ cen_ws, float* __restrict__ cen_out)
{
    int t = threadIdx.x;
    if (t < 48) {
        int b = t / 6;
        int k = t % 6;
        double acc = 0.0;
        for (int ic = 0; ic < 32; ++ic) acc = fma((double)w3[k * 32 + ic], ybar[b * 32 + ic], acc);
        double inv = (double)g[k] / sqrt((double)vr[k] + BN_EPS);
        double c = acc * inv + ((double)be[k] - (double)mn[k] * inv);
        cen_ws[t]  = c;
        cen_out[t] = (float)c;
    }
}

// ============ quantization: fp64 dist/argmin, fp32 softmax; float4 I/O ============
__global__ __launch_bounds__(256) void quant_kernel(
    const float* __restrict__ x, const double* __restrict__ centers,
    float* __restrict__ qbar, float* __restrict__ qsoft,
    float* __restrict__ qhard, float* __restrict__ sym)
{
    int vid = blockIdx.x * 256 + threadIdx.x;   // float4 index; 2^17 vecs per batch
    int b = vid >> 17;

    double c[6];
    float cf[6];
    #pragma unroll
    for (int k = 0; k < 6; ++k) { c[k] = centers[b * 6 + k]; cf[k] = (float)c[k]; }

    float4 xv = ((const float4*)x)[vid];
    float xs[4] = {xv.x, xv.y, xv.z, xv.w};
    float r_bar[4], r_soft[4], r_hard[4], r_sym[4];

    #pragma unroll
    for (int i = 0; i < 4; ++i) {
        double xx = (double)xs[i];
        double d[6];
        double dmin = 1e300;
        int amin = 0;
        #pragma unroll
        for (int k = 0; k < 6; ++k) {
            double t = xx - c[k];
            d[k] = t * t;
            if (d[k] < dmin) { dmin = d[k]; amin = k; }
        }
        float se = 0.f, sw = 0.f;
        #pragma unroll
        for (int k = 0; k < 6; ++k) {
            float e = __expf(SIGMA * (float)(dmin - d[k]));
            se += e;
            sw += e * cf[k];
        }
        float qs = sw / se;
        float qh = cf[amin];
        r_soft[i] = qs;
        r_hard[i] = qh;
        r_bar[i]  = qh;
        r_sym[i]  = (float)amin;
    }

    ((float4*)qbar)[vid]  = make_float4(r_bar[0],  r_bar[1],  r_bar[2],  r_bar[3]);
    ((float4*)qsoft)[vid] = make_float4(r_soft[0], r_soft[1], r_soft[2], r_soft[3]);
    ((float4*)qhard)[vid] = make_float4(r_hard[0], r_hard[1], r_hard[2], r_hard[3]);
    ((float4*)sym)[vid]   = make_float4(r_sym[0],  r_sym[1],  r_sym[2],  r_sym[3]);
}

extern "C" void kernel_launch(void* const* d_in, const int* in_sizes, int n_in,
                              void* d_out, int out_size, void* d_ws, size_t ws_size,
                              hipStream_t stream) {
    const float* x  = (const float*)d_in[0];
    const float* cf = (const float*)d_in[1];
    const float* w1 = (const float*)d_in[2];
    const float* g1 = (const float*)d_in[3];
    const float* b1 = (const float*)d_in[4];
    const float* m1 = (const float*)d_in[5];
    const float* v1 = (const float*)d_in[6];
    const float* w2 = (const float*)d_in[7];
    const float* g2 = (const float*)d_in[8];
    const float* b2 = (const float*)d_in[9];
    const float* m2 = (const float*)d_in[10];
    const float* v2 = (const float*)d_in[11];
    const float* w3 = (const float*)d_in[12];
    const float* g3 = (const float*)d_in[13];
    const float* b3 = (const float*)d_in[14];
    const float* m3 = (const float*)d_in[15];
    const float* v3 = (const float*)d_in[16];

    const int NELEM = 8 * 128 * 64 * 64;      // 4,194,304
    float* out   = (float*)d_out;
    float* qbar  = out;
    float* qsoft = out + (size_t)NELEM;
    float* qhard = out + (size_t)2 * NELEM;
    float* sym   = out + (size_t)3 * NELEM;
    float* cen_o = out + (size_t)4 * NELEM;

    char* ws = (char*)d_ws;
    float*  part1 = (float*)(ws);                        // 8 x 524288 f32 = 16 MB
    float*  part2 = (float*)(ws + 16777216);             // 16 x 65536 f32 = 4 MB
    double* yb    = (double*)(ws + 20971520);            // 256 f64
    double* cen   = (double*)(ws + 20973568);            // 48 f64   (~21 MB total)

    conv1_partial_kernel<<<1024, 128, 0, stream>>>(cf, w1, part1);
    conv2_partial_kernel<<<512, 256, 0, stream>>>(part1, g1, b1, m1, v1, w2, part2);
    conv2_combine_ybar_kernel<<<256, 256, 0, stream>>>(part2, g2, b2, m2, v2, yb);
    centers_kernel<<<1, 64, 0, stream>>>(yb, w3, g3, b3, m3, v3, cen, cen_o);
    quant_kernel<<<NELEM / 4 / 256, 256, 0, stream>>>(x, cen, qbar, qsoft, qhard, sym);
}

// Round 7
// 210.137 us; speedup vs baseline: 2.3177x; 2.3177x over previous
//
#include <hip/hip_runtime.h>
#include <math.h>

#define BN_EPS 1e-5
#define SIGMA 1.0f

typedef double f64x4 __attribute__((ext_vector_type(4)));

// ============ conv1 via fp64 MFMA implicit GEMM ============
// C[m=pixel][n=oc] = sum_k A[m][k] B[k][n], k = (kh,kw) major, ic minor (commutative reorder)
// grid 1024 = ksp(8: 16 ic) x b(8) x mt(16: oh pair); block 256 = 4 waves
// wave (wm,wn): 32m x 32n tile = 2x2 mfma_f64_16x16x4 fragments, K_split = 144
// LDS: input f32 [16][5][67] (c = iw+1, pad col), weights f32 [9][16][65]; ~58.9 KB
// A: M=l&15, K=l>>4; B: N=l&15, K=l>>4 (standard 16x16 maps).
// D row map for f64 is PROBED at runtime (r6 failed on the assumed 4*(l>>4)+reg map;
// CDNA2-era f64 instruction was not covered by the gfx950 16x16 C/D measurements).
__global__ __launch_bounds__(256) void conv1_mfma_kernel(
    const float* __restrict__ in, const float* __restrict__ w1,
    float* __restrict__ part)
{
    __shared__ float sin_[16 * 5 * 67];   // 5360 f32, row stride 67, ic stride 335
    __shared__ float swt[9 * 16 * 65];    // 9360 f32

    int bid = blockIdx.x;
    int mt  = bid & 15;            // oh0 = 2*mt
    int b   = (bid >> 4) & 7;
    int ksp = bid >> 7;            // 16 ic per split

    int tid = threadIdx.x;
    int l   = tid & 63;
    int wv  = tid >> 6;            // 0..3
    int wm  = wv >> 1;             // oh = 2*mt + wm
    int wn  = wv & 1;              // oc base = wn*32

    // ---- D-layout probe: A[m][k] = m (a = l&15), B = delta(k==0,n==0) (lane 0 only)
    //      => D[m][0] = m. Lanes 0,16,32,48 hold col 0; their reg r value IS the row index.
    double ap = (double)(l & 15);
    double bp = (l == 0) ? 1.0 : 0.0;
    f64x4 dp = {0., 0., 0., 0.};
    dp = __builtin_amdgcn_mfma_f64_16x16x4f64(ap, bp, dp, 0, 0, 0);
    int row0[4];
    #pragma unroll
    for (int r = 0; r < 4; ++r)
        row0[r] = ((int)__shfl(dp[r], (l & 0x30), 64)) & 15;

    // ---- stage input band: ih = 4*mt-1 .. 4*mt+3, iw = -1..63 (c=iw+1), zero pad
    const float* ib = in + (size_t)(b * 128 + ksp * 16) * 4096;
    int ih_base = 4 * mt - 1;
    for (int i = tid; i < 5360; i += 256) {
        int ic  = i / 335;
        int rem = i % 335;
        int r   = rem / 67;
        int c   = rem % 67;
        int ih  = ih_base + r;
        int iw  = c - 1;
        float v = 0.f;
        if ((unsigned)ih < 64u && (unsigned)iw < 64u)
            v = ib[(ic * 64 + ih) * 64 + iw];
        sin_[i] = v;
    }
    // ---- stage weights: swt[khw][ic][n] = w1[n][ksp*16+ic][khw]  (OIHW)
    for (int i = tid; i < 9360; i += 256) {
        int khw = i / 1040;
        int rem = i % 1040;
        int ic  = rem / 65;
        int n   = rem % 65;
        float v = 0.f;
        if (n < 64)
            v = w1[(n * 128 + ksp * 16 + ic) * 9 + khw];
        swt[i] = v;
    }
    __syncthreads();

    f64x4 d00 = {0., 0., 0., 0.}, d01 = {0., 0., 0., 0.};
    f64x4 d10 = {0., 0., 0., 0.}, d11 = {0., 0., 0., 0.};

    // per-lane bases (dword units):
    const float* pa = &sin_[(l >> 4) * 335 + 2 * wm * 67 + 2 * (l & 15)];
    const float* pb = &swt[(l >> 4) * 65 + wn * 32 + (l & 15)];

    #pragma unroll
    for (int khw = 0; khw < 9; ++khw) {
        int kh = khw / 3;
        int kw = khw - 3 * kh;
        #pragma unroll
        for (int icb = 0; icb < 4; ++icb) {
            double a0 = (double)pa[icb * 1340 + kh * 67 + kw];
            double a1 = (double)pa[icb * 1340 + kh * 67 + kw + 32];
            double b0 = (double)pb[(khw * 16 + icb * 4) * 65];
            double b1 = (double)pb[(khw * 16 + icb * 4) * 65 + 16];
            d00 = __builtin_amdgcn_mfma_f64_16x16x4f64(a0, b0, d00, 0, 0, 0);
            d01 = __builtin_amdgcn_mfma_f64_16x16x4f64(a0, b1, d01, 0, 0, 0);
            d10 = __builtin_amdgcn_mfma_f64_16x16x4f64(a1, b0, d10, 0, 0, 0);
            d11 = __builtin_amdgcn_mfma_f64_16x16x4f64(a1, b1, d11, 0, 0, 0);
        }
    }

    __syncthreads();
    // ---- transpose D through LDS (reuse sin_: 64*65 = 4160 f32) using PROBED row map
    float* so = sin_;
    #pragma unroll
    for (int mi = 0; mi < 2; ++mi) {
        f64x4 v0 = mi ? d10 : d00;   // ni = 0
        f64x4 v1 = mi ? d11 : d01;   // ni = 1
        #pragma unroll
        for (int r = 0; r < 4; ++r) {
            int m   = wm * 32 + mi * 16 + row0[r];
            int oc0 = wn * 32 + (l & 15);
            so[oc0 * 65 + m]        = (float)v0[r];
            so[(oc0 + 16) * 65 + m] = (float)v1[r];
        }
    }
    __syncthreads();
    int oh0 = 2 * mt;
    for (int i = tid; i < 4096; i += 256) {
        int oc = i >> 6;
        int m  = i & 63;
        part[(size_t)ksp * 524288 +
             ((b * 64 + oc) * 32 + oh0 + (m >> 5)) * 32 + (m & 31)] = so[oc * 65 + m];
    }
}

// ============ conv2 partial, FUSED with conv1-combine (sum 8 partials + BN1 + ReLU) =========
// grid 512 = isp(16: 4 ic) x b(8) x ocg(4); block 256 = full 16x16 spatial
__global__ __launch_bounds__(256) void conv2_partial_kernel(
    const float* __restrict__ part1,
    const float* __restrict__ g1, const float* __restrict__ be1,
    const float* __restrict__ mn1, const float* __restrict__ vr1,
    const float* __restrict__ w,
    float* __restrict__ part)
{
    __shared__ float tin[4][33][36];
    __shared__ float twt[4][9][8];
    __shared__ double sinv[4], ssh[4];

    int bid = blockIdx.x;
    int ocg = bid & 3;
    int b   = (bid >> 2) & 7;
    int isp = bid >> 5;

    int tid = threadIdx.x;
    int ow  = tid & 15;
    int oh  = tid >> 4;

    if (tid < 4) {
        int ch = isp * 4 + tid;
        double inv = (double)g1[ch] / sqrt((double)vr1[ch] + BN_EPS);
        sinv[tid] = inv;
        ssh[tid]  = (double)be1[ch] - (double)mn1[ch] * inv;
    }
    __syncthreads();

    for (int lin = tid; lin < 4 * 33 * 34; lin += 256) {
        int c   = lin % 34;
        int t2  = lin / 34;
        int rr  = t2 % 33;
        int icc = t2 / 33;
        int ih  = rr - 1;
        int iw  = c - 1;
        float v = 0.f;
        if ((unsigned)ih < 32u && (unsigned)iw < 32u) {
            int ch  = isp * 4 + icc;
            int idx = ((b * 64 + ch) * 32 + ih) * 32 + iw;
            double s = 0.0;
            #pragma unroll
            for (int p = 0; p < 8; ++p) s += (double)part1[idx + p * 524288];
            double o = s * sinv[icc] + ssh[icc];
            v = fmaxf((float)o, 0.f);
        }
        tin[icc][rr][c] = v;
    }
    for (int i = tid; i < 288; i += 256) {
        int j   = i & 7;
        int k   = (i >> 3) % 9;
        int icc = i / 72;
        twt[icc][k][j] = w[(ocg * 8 + j) * 576 + (isp * 4 + icc) * 9 + k];
    }
    __syncthreads();

    double acc[8];
    #pragma unroll
    for (int j = 0; j < 8; ++j) acc[j] = 0.0;

    for (int icc = 0; icc < 4; ++icc) {
        double xv[9];
        #pragma unroll
        for (int kh = 0; kh < 3; ++kh)
            #pragma unroll
            for (int kw = 0; kw < 3; ++kw)
                xv[kh * 3 + kw] = (double)tin[icc][2 * oh + kh][2 * ow + kw];
        #pragma unroll
        for (int k = 0; k < 9; ++k) {
            float4 wa = *(const float4*)&twt[icc][k][0];
            float4 wb = *(const float4*)&twt[icc][k][4];
            acc[0] = fma(xv[k], (double)wa.x, acc[0]);
            acc[1] = fma(xv[k], (double)wa.y, acc[1]);
            acc[2] = fma(xv[k], (double)wa.z, acc[2]);
            acc[3] = fma(xv[k], (double)wa.w, acc[3]);
            acc[4] = fma(xv[k], (double)wb.x, acc[4]);
            acc[5] = fma(xv[k], (double)wb.y, acc[5]);
            acc[6] = fma(xv[k], (double)wb.z, acc[6]);
            acc[7] = fma(xv[k], (double)wb.w, acc[7]);
        }
    }
    int obase = ((b * 32 + ocg * 8) * 16 + oh) * 16 + ow;
    #pragma unroll
    for (int j = 0; j < 8; ++j)
        part[isp * 65536 + obase + j * 256] = (float)acc[j];
}

// ============ conv2 combine + BN + ReLU + spatial mean -> ybar[256] ============
__global__ __launch_bounds__(256) void conv2_combine_ybar_kernel(
    const float* __restrict__ part,
    const float* __restrict__ g, const float* __restrict__ be,
    const float* __restrict__ mn, const float* __restrict__ vr,
    double* __restrict__ ybar)
{
    __shared__ double sm[4];
    int j  = blockIdx.x;             // j = b*32 + oc
    int oc = j & 31;
    int t  = threadIdx.x;
    int idx = j * 256 + t;
    double s = 0.0;
    #pragma unroll
    for (int p = 0; p < 16; ++p) s += (double)part[idx + p * 65536];
    double inv = (double)g[oc] / sqrt((double)vr[oc] + BN_EPS);
    double o = s * inv + ((double)be[oc] - (double)mn[oc] * inv);
    double v = fmax(o, 0.0);
    #pragma unroll
    for (int off = 32; off > 0; off >>= 1) v += __shfl_down(v, off, 64);
    if ((t & 63) == 0) sm[t >> 6] = v;
    __syncthreads();
    if (t == 0) ybar[j] = (sm[0] + sm[1] + sm[2] + sm[3]) * (1.0 / 256.0);
}

// ============ centers: conv3(1x1)+BN folded with the spatial mean, fp64 ============
__global__ __launch_bounds__(64) void centers_kernel(
    const double* __restrict__ ybar, const float* __restrict__ w3,
    const float* __restrict__ g, const float* __restrict__ be,
    const float* __restrict__ mn, const float* __restrict__ vr,
    double* __restrict__ cen_ws, float* __restrict__ cen_out)
{
    int t = threadIdx.x;
    if (t < 48) {
        int b = t / 6;
        int k = t % 6;
        double acc = 0.0;
        for (int ic = 0; ic < 32; ++ic) acc = fma((double)w3[k * 32 + ic], ybar[b * 32 + ic], acc);
        double inv = (double)g[k] / sqrt((double)vr[k] + BN_EPS);
        double c = acc * inv + ((double)be[k] - (double)mn[k] * inv);
        cen_ws[t]  = c;
        cen_out[t] = (float)c;
    }
}

// ============ quantization: fp64 dist/argmin, fp32 softmax; float4 I/O ============
__global__ __launch_bounds__(256) void quant_kernel(
    const float* __restrict__ x, const double* __restrict__ centers,
    float* __restrict__ qbar, float* __restrict__ qsoft,
    float* __restrict__ qhard, float* __restrict__ sym)
{
    int vid = blockIdx.x * 256 + threadIdx.x;   // float4 index; 2^17 vecs per batch
    int b = vid >> 17;

    double c[6];
    float cf[6];
    #pragma unroll
    for (int k = 0; k < 6; ++k) { c[k] = centers[b * 6 + k]; cf[k] = (float)c[k]; }

    float4 xv = ((const float4*)x)[vid];
    float xs[4] = {xv.x, xv.y, xv.z, xv.w};
    float r_bar[4], r_soft[4], r_hard[4], r_sym[4];

    #pragma unroll
    for (int i = 0; i < 4; ++i) {
        double xx = (double)xs[i];
        double d[6];
        double dmin = 1e300;
        int amin = 0;
        #pragma unroll
        for (int k = 0; k < 6; ++k) {
            double t = xx - c[k];
            d[k] = t * t;
            if (d[k] < dmin) { dmin = d[k]; amin = k; }
        }
        float se = 0.f, sw = 0.f;
        #pragma unroll
        for (int k = 0; k < 6; ++k) {
            float e = __expf(SIGMA * (float)(dmin - d[k]));
            se += e;
            sw += e * cf[k];
        }
        float qs = sw / se;
        float qh = cf[amin];
        r_soft[i] = qs;
        r_hard[i] = qh;
        r_bar[i]  = qh;
        r_sym[i]  = (float)amin;
    }

    ((float4*)qbar)[vid]  = make_float4(r_bar[0],  r_bar[1],  r_bar[2],  r_bar[3]);
    ((float4*)qsoft)[vid] = make_float4(r_soft[0], r_soft[1], r_soft[2], r_soft[3]);
    ((float4*)qhard)[vid] = make_float4(r_hard[0], r_hard[1], r_hard[2], r_hard[3]);
    ((float4*)sym)[vid]   = make_float4(r_sym[0],  r_sym[1],  r_sym[2],  r_sym[3]);
}

extern "C" void kernel_launch(void* const* d_in, const int* in_sizes, int n_in,
                              void* d_out, int out_size, void* d_ws, size_t ws_size,
                              hipStream_t stream) {
    const float* x  = (const float*)d_in[0];
    const float* cf = (const float*)d_in[1];
    const float* w1 = (const float*)d_in[2];
    const float* g1 = (const float*)d_in[3];
    const float* b1 = (const float*)d_in[4];
    const float* m1 = (const float*)d_in[5];
    const float* v1 = (const float*)d_in[6];
    const float* w2 = (const float*)d_in[7];
    const float* g2 = (const float*)d_in[8];
    const float* b2 = (const float*)d_in[9];
    const float* m2 = (const float*)d_in[10];
    const float* v2 = (const float*)d_in[11];
    const float* w3 = (const float*)d_in[12];
    const float* g3 = (const float*)d_in[13];
    const float* b3 = (const float*)d_in[14];
    const float* m3 = (const float*)d_in[15];
    const float* v3 = (const float*)d_in[16];

    const int NELEM = 8 * 128 * 64 * 64;      // 4,194,304
    float* out   = (float*)d_out;
    float* qbar  = out;
    float* qsoft = out + (size_t)NELEM;
    float* qhard = out + (size_t)2 * NELEM;
    float* sym   = out + (size_t)3 * NELEM;
    float* cen_o = out + (size_t)4 * NELEM;

    char* ws = (char*)d_ws;
    float*  part1 = (float*)(ws);                        // 8 x 524288 f32 = 16 MB
    float*  part2 = (float*)(ws + 16777216);             // 16 x 65536 f32 = 4 MB
    double* yb    = (double*)(ws + 20971520);            // 256 f64
    double* cen   = (double*)(ws + 20973568);            // 48 f64   (~21 MB total)

    conv1_mfma_kernel<<<1024, 256, 0, stream>>>(cf, w1, part1);
    conv2_partial_kernel<<<512, 256, 0, stream>>>(part1, g1, b1, m1, v1, w2, part2);
    conv2_combine_ybar_kernel<<<256, 256, 0, stream>>>(part2, g2, b2, m2, v2, yb);
    centers_kernel<<<1, 64, 0, stream>>>(yb, w3, g3, b3, m3, v3, cen, cen_o);
    quant_kernel<<<NELEM / 4 / 256, 256, 0, stream>>>(x, cen, qbar, qsoft, qhard, sym);
}

// Round 8
// 187.880 us; speedup vs baseline: 2.5922x; 1.1185x over previous
//
#include <hip/hip_runtime.h>
#include <math.h>

#define BN_EPS 1e-5
#define SIGMA 1.0f

typedef double f64x4 __attribute__((ext_vector_type(4)));

// ============ conv1 via fp64 MFMA implicit GEMM (v2: global-A, interleaved-B, 4 blk/CU) ====
// C[m=pixel][n=oc] = sum_k A[m][k] B[k][n], k = (kh,kw) major, ic minor
// grid 1024 = ksp(8: 16 ic) x b(8) x mt(16: oh pair); block 256 = 4 waves (wm x wn)
// wave: 32m x 32n = 2x2 mfma_f64_16x16x4 fragments, 144 MFMAs
// A read DIRECT from global (L1-resident band, per-lane base + immediate offsets)
// B in LDS [khw][icb][n(64)][lg(4)] = 36.9 KB (lanes read consecutive dwords, conflict-free)
// -> 4 blocks/CU = 4 waves/SIMD: enough to saturate the 64-cy f64 MFMA pipe.
// D row map probed at runtime (r7-verified). Math order identical to r7 -> bit-identical.
__global__ __launch_bounds__(256, 4) void conv1_mfma_kernel(
    const float* __restrict__ in, const float* __restrict__ w1,
    float* __restrict__ part)
{
    __shared__ float swt[9216];   // [khw][icb][n][lg]; reused as output-transpose buffer

    int bid = blockIdx.x;
    int mt  = bid & 15;            // oh0 = 2*mt
    int b   = (bid >> 4) & 7;
    int ksp = bid >> 7;            // 16 ic per split

    int tid = threadIdx.x;
    int l   = tid & 63;
    int wv  = tid >> 6;            // 0..3
    int wm  = wv >> 1;             // oh = 2*mt + wm
    int wn  = wv & 1;              // oc base = wn*32
    int lc  = l & 15;
    int lg  = l >> 4;              // 0..3

    // ---- D-layout probe: A[m][0..3] = m, B = delta(k==0,n==0) => D[m][0] = m.
    //      Lanes with lc==0 hold col 0; their reg r value IS the row index for the group.
    double ap = (double)lc;
    double bp = (l == 0) ? 1.0 : 0.0;
    f64x4 dp = {0., 0., 0., 0.};
    dp = __builtin_amdgcn_mfma_f64_16x16x4f64(ap, bp, dp, 0, 0, 0);
    int row0[4];
    #pragma unroll
    for (int r = 0; r < 4; ++r)
        row0[r] = ((int)__shfl(dp[r], (l & 0x30), 64)) & 15;

    // ---- stage weights: swt[((khw*4+icb)*64 + n)*4 + g] = w1[n][ksp*16 + icb*4 + g][khw]
    for (int i = tid; i < 9216; i += 256) {
        int g   = i & 3;
        int n   = (i >> 2) & 63;
        int kic = i >> 8;           // khw*4 + icb
        int khw = kic >> 2;
        int icb = kic & 3;
        swt[i] = w1[(n * 128 + ksp * 16 + icb * 4 + g) * 9 + khw];
    }
    __syncthreads();

    f64x4 d00 = {0., 0., 0., 0.}, d01 = {0., 0., 0., 0.};
    f64x4 d10 = {0., 0., 0., 0.}, d11 = {0., 0., 0., 0.};

    // A addressing: channel = ksp*16 + icb*4 + lg (lg in base, icb via offset)
    const float* cb = in + (size_t)(b * 128 + ksp * 16 + lg) * 4096;
    int r0 = 4 * mt + 2 * wm - 1;                       // ih for kh==0 (wave-uniform)
    const float* pbase = cb + (ptrdiff_t)(r0 * 64 + 2 * lc - 1);
    bool c0ok = (lc != 0);

    // B per-lane base: n = wn*32 + lc (+16 for b1), k-slot = lg
    const float* pB = swt + (wn * 32 + lc) * 4 + lg;

    #pragma unroll
    for (int khw = 0; khw < 9; ++khw) {
        const int kh = khw / 3;
        const int kw = khw - 3 * kh;
        bool rowok = (kh > 0) || (r0 >= 0);             // r0 >= -1 always
        #pragma unroll
        for (int icb = 0; icb < 4; ++icb) {
            const int offA = icb * 16384 + kh * 64 + kw;
            bool ok0 = rowok && ((kw > 0) || c0ok);
            const float* q0 = ok0 ? (pbase + offA) : cb;        // cb always valid
            float f0 = *q0;
            double a0 = ok0 ? (double)f0 : 0.0;
            const float* q1 = rowok ? (pbase + offA + 32) : cb; // a1 col >= 30: row-check only
            float f1 = *q1;
            double a1 = rowok ? (double)f1 : 0.0;

            const int offB = (khw * 4 + icb) * 256;
            double b0 = (double)pB[offB];
            double b1 = (double)pB[offB + 64];

            d00 = __builtin_amdgcn_mfma_f64_16x16x4f64(a0, b0, d00, 0, 0, 0);
            d01 = __builtin_amdgcn_mfma_f64_16x16x4f64(a0, b1, d01, 0, 0, 0);
            d10 = __builtin_amdgcn_mfma_f64_16x16x4f64(a1, b0, d10, 0, 0, 0);
            d11 = __builtin_amdgcn_mfma_f64_16x16x4f64(a1, b1, d11, 0, 0, 0);
        }
    }

    __syncthreads();   // weights no longer needed; reuse swt as transpose buffer
    float* so = swt;   // 64 oc x 65: 4160 floats < 9216
    #pragma unroll
    for (int mi = 0; mi < 2; ++mi) {
        f64x4 v0 = mi ? d10 : d00;   // ni = 0
        f64x4 v1 = mi ? d11 : d01;   // ni = 1
        #pragma unroll
        for (int r = 0; r < 4; ++r) {
            int m   = wm * 32 + mi * 16 + row0[r];
            int oc0 = wn * 32 + lc;
            so[oc0 * 65 + m]        = (float)v0[r];
            so[(oc0 + 16) * 65 + m] = (float)v1[r];
        }
    }
    __syncthreads();
    int oh0 = 2 * mt;
    for (int i = tid; i < 4096; i += 256) {
        int oc = i >> 6;
        int m  = i & 63;
        part[(size_t)ksp * 524288 +
             ((b * 64 + oc) * 32 + oh0 + (m >> 5)) * 32 + (m & 31)] = so[oc * 65 + m];
    }
}

// ============ conv2 partial, FUSED with conv1-combine (sum 8 partials + BN1 + ReLU) =========
// grid 512 = isp(16: 4 ic) x b(8) x ocg(4); block 256 = full 16x16 spatial
__global__ __launch_bounds__(256) void conv2_partial_kernel(
    const float* __restrict__ part1,
    const float* __restrict__ g1, const float* __restrict__ be1,
    const float* __restrict__ mn1, const float* __restrict__ vr1,
    const float* __restrict__ w,
    float* __restrict__ part)
{
    __shared__ float tin[4][33][36];
    __shared__ float twt[4][9][8];
    __shared__ double sinv[4], ssh[4];

    int bid = blockIdx.x;
    int ocg = bid & 3;
    int b   = (bid >> 2) & 7;
    int isp = bid >> 5;

    int tid = threadIdx.x;
    int ow  = tid & 15;
    int oh  = tid >> 4;

    if (tid < 4) {
        int ch = isp * 4 + tid;
        double inv = (double)g1[ch] / sqrt((double)vr1[ch] + BN_EPS);
        sinv[tid] = inv;
        ssh[tid]  = (double)be1[ch] - (double)mn1[ch] * inv;
    }
    __syncthreads();

    for (int lin = tid; lin < 4 * 33 * 34; lin += 256) {
        int c   = lin % 34;
        int t2  = lin / 34;
        int rr  = t2 % 33;
        int icc = t2 / 33;
        int ih  = rr - 1;
        int iw  = c - 1;
        float v = 0.f;
        if ((unsigned)ih < 32u && (unsigned)iw < 32u) {
            int ch  = isp * 4 + icc;
            int idx = ((b * 64 + ch) * 32 + ih) * 32 + iw;
            double s = 0.0;
            #pragma unroll
            for (int p = 0; p < 8; ++p) s += (double)part1[idx + p * 524288];
            double o = s * sinv[icc] + ssh[icc];
            v = fmaxf((float)o, 0.f);
        }
        tin[icc][rr][c] = v;
    }
    for (int i = tid; i < 288; i += 256) {
        int j   = i & 7;
        int k   = (i >> 3) % 9;
        int icc = i / 72;
        twt[icc][k][j] = w[(ocg * 8 + j) * 576 + (isp * 4 + icc) * 9 + k];
    }
    __syncthreads();

    double acc[8];
    #pragma unroll
    for (int j = 0; j < 8; ++j) acc[j] = 0.0;

    for (int icc = 0; icc < 4; ++icc) {
        double xv[9];
        #pragma unroll
        for (int kh = 0; kh < 3; ++kh)
            #pragma unroll
            for (int kw = 0; kw < 3; ++kw)
                xv[kh * 3 + kw] = (double)tin[icc][2 * oh + kh][2 * ow + kw];
        #pragma unroll
        for (int k = 0; k < 9; ++k) {
            float4 wa = *(const float4*)&twt[icc][k][0];
            float4 wb = *(const float4*)&twt[icc][k][4];
            acc[0] = fma(xv[k], (double)wa.x, acc[0]);
            acc[1] = fma(xv[k], (double)wa.y, acc[1]);
            acc[2] = fma(xv[k], (double)wa.z, acc[2]);
            acc[3] = fma(xv[k], (double)wa.w, acc[3]);
            acc[4] = fma(xv[k], (double)wb.x, acc[4]);
            acc[5] = fma(xv[k], (double)wb.y, acc[5]);
            acc[6] = fma(xv[k], (double)wb.z, acc[6]);
            acc[7] = fma(xv[k], (double)wb.w, acc[7]);
        }
    }
    int obase = ((b * 32 + ocg * 8) * 16 + oh) * 16 + ow;
    #pragma unroll
    for (int j = 0; j < 8; ++j)
        part[isp * 65536 + obase + j * 256] = (float)acc[j];
}

// ============ conv2 combine + BN + ReLU + spatial mean -> ybar[256] ============
__global__ __launch_bounds__(256) void conv2_combine_ybar_kernel(
    const float* __restrict__ part,
    const float* __restrict__ g, const float* __restrict__ be,
    const float* __restrict__ mn, const float* __restrict__ vr,
    double* __restrict__ ybar)
{
    __shared__ double sm[4];
    int j  = blockIdx.x;             // j = b*32 + oc
    int oc = j & 31;
    int t  = threadIdx.x;
    int idx = j * 256 + t;
    double s = 0.0;
    #pragma unroll
    for (int p = 0; p < 16; ++p) s += (double)part[idx + p * 65536];
    double inv = (double)g[oc] / sqrt((double)vr[oc] + BN_EPS);
    double o = s * inv + ((double)be[oc] - (double)mn[oc] * inv);
    double v = fmax(o, 0.0);
    #pragma unroll
    for (int off = 32; off > 0; off >>= 1) v += __shfl_down(v, off, 64);
    if ((t & 63) == 0) sm[t >> 6] = v;
    __syncthreads();
    if (t == 0) ybar[j] = (sm[0] + sm[1] + sm[2] + sm[3]) * (1.0 / 256.0);
}

// ============ centers: conv3(1x1)+BN folded with the spatial mean, fp64 ============
__global__ __launch_bounds__(64) void centers_kernel(
    const double* __restrict__ ybar, const float* __restrict__ w3,
    const float* __restrict__ g, const float* __restrict__ be,
    const float* __restrict__ mn, const float* __restrict__ vr,
    double* __restrict__ cen_ws, float* __restrict__ cen_out)
{
    int t = threadIdx.x;
    if (t < 48) {
        int b = t / 6;
        int k = t % 6;
        double acc = 0.0;
        for (int ic = 0; ic < 32; ++ic) acc = fma((double)w3[k * 32 + ic], ybar[b * 32 + ic], acc);
        double inv = (double)g[k] / sqrt((double)vr[k] + BN_EPS);
        double c = acc * inv + ((double)be[k] - (double)mn[k] * inv);
        cen_ws[t]  = c;
        cen_out[t] = (float)c;
    }
}

// ============ quantization: fp64 dist/argmin, fp32 softmax; float4 I/O ============
__global__ __launch_bounds__(256) void quant_kernel(
    const float* __restrict__ x, const double* __restrict__ centers,
    float* __restrict__ qbar, float* __restrict__ qsoft,
    float* __restrict__ qhard, float* __restrict__ sym)
{
    int vid = blockIdx.x * 256 + threadIdx.x;   // float4 index; 2^17 vecs per batch
    int b = vid >> 17;

    double c[6];
    float cf[6];
    #pragma unroll
    for (int k = 0; k < 6; ++k) { c[k] = centers[b * 6 + k]; cf[k] = (float)c[k]; }

    float4 xv = ((const float4*)x)[vid];
    float xs[4] = {xv.x, xv.y, xv.z, xv.w};
    float r_bar[4], r_soft[4], r_hard[4], r_sym[4];

    #pragma unroll
    for (int i = 0; i < 4; ++i) {
        double xx = (double)xs[i];
        double d[6];
        double dmin = 1e300;
        int amin = 0;
        #pragma unroll
        for (int k = 0; k < 6; ++k) {
            double t = xx - c[k];
            d[k] = t * t;
            if (d[k] < dmin) { dmin = d[k]; amin = k; }
        }
        float se = 0.f, sw = 0.f;
        #pragma unroll
        for (int k = 0; k < 6; ++k) {
            float e = __expf(SIGMA * (float)(dmin - d[k]));
            se += e;
            sw += e * cf[k];
        }
        float qs = sw / se;
        float qh = cf[amin];
        r_soft[i] = qs;
        r_hard[i] = qh;
        r_bar[i]  = qh;
        r_sym[i]  = (float)amin;
    }

    ((float4*)qbar)[vid]  = make_float4(r_bar[0],  r_bar[1],  r_bar[2],  r_bar[3]);
    ((float4*)qsoft)[vid] = make_float4(r_soft[0], r_soft[1], r_soft[2], r_soft[3]);
    ((float4*)qhard)[vid] = make_float4(r_hard[0], r_hard[1], r_hard[2], r_hard[3]);
    ((float4*)sym)[vid]   = make_float4(r_sym[0],  r_sym[1],  r_sym[2],  r_sym[3]);
}

extern "C" void kernel_launch(void* const* d_in, const int* in_sizes, int n_in,
                              void* d_out, int out_size, void* d_ws, size_t ws_size,
                              hipStream_t stream) {
    const float* x  = (const float*)d_in[0];
    const float* cf = (const float*)d_in[1];
    const float* w1 = (const float*)d_in[2];
    const float* g1 = (const float*)d_in[3];
    const float* b1 = (const float*)d_in[4];
    const float* m1 = (const float*)d_in[5];
    const float* v1 = (const float*)d_in[6];
    const float* w2 = (const float*)d_in[7];
    const float* g2 = (const float*)d_in[8];
    const float* b2 = (const float*)d_in[9];
    const float* m2 = (const float*)d_in[10];
    const float* v2 = (const float*)d_in[11];
    const float* w3 = (const float*)d_in[12];
    const float* g3 = (const float*)d_in[13];
    const float* b3 = (const float*)d_in[14];
    const float* m3 = (const float*)d_in[15];
    const float* v3 = (const float*)d_in[16];

    const int NELEM = 8 * 128 * 64 * 64;      // 4,194,304
    float* out   = (float*)d_out;
    float* qbar  = out;
    float* qsoft = out + (size_t)NELEM;
    float* qhard = out + (size_t)2 * NELEM;
    float* sym   = out + (size_t)3 * NELEM;
    float* cen_o = out + (size_t)4 * NELEM;

    char* ws = (char*)d_ws;
    float*  part1 = (float*)(ws);                        // 8 x 524288 f32 = 16 MB
    float*  part2 = (float*)(ws + 16777216);             // 16 x 65536 f32 = 4 MB
    double* yb    = (double*)(ws + 20971520);            // 256 f64
    double* cen   = (double*)(ws + 20973568);            // 48 f64   (~21 MB total)

    conv1_mfma_kernel<<<1024, 256, 0, stream>>>(cf, w1, part1);
    conv2_partial_kernel<<<512, 256, 0, stream>>>(part1, g1, b1, m1, v1, w2, part2);
    conv2_combine_ybar_kernel<<<256, 256, 0, stream>>>(part2, g2, b2, m2, v2, yb);
    centers_kernel<<<1, 64, 0, stream>>>(yb, w3, g3, b3, m3, v3, cen, cen_o);
    quant_kernel<<<NELEM / 4 / 256, 256, 0, stream>>>(x, cen, qbar, qsoft, qhard, sym);
}

// Round 9
// 183.820 us; speedup vs baseline: 2.6495x; 1.0221x over previous
//
#include <hip/hip_runtime.h>
#include <math.h>

#define BN_EPS 1e-5
#define SIGMA 1.0f

typedef double f64x4 __attribute__((ext_vector_type(4)));

// ============ conv1 via fp64 MFMA implicit GEMM (v3: kh-level double-buffered A prefetch) ==
// C[m=pixel][n=oc] = sum_k A[m][k] B[k][n], k = (kh,kw) major, ic minor
// grid 1024 = ksp(8: 16 ic) x b(8) x mt(16); block 256 = 4 waves (wm x wn)
// Per kh phase: issue 24 A-loads for NEXT kh (dbuf regs), then 48 MFMAs (3072 cy pipe)
// -> load latency hidden under MFMA phase. MFMA order identical to r8 -> bit-identical.
// B in LDS [khw][icb][n(64)][lg(4)] = 36.9 KB; D row map probed at runtime (r7-verified).
__global__ __launch_bounds__(256, 4) void conv1_mfma_kernel(
    const float* __restrict__ in, const float* __restrict__ w1,
    float* __restrict__ part)
{
    __shared__ float swt[9216];   // weights; reused as output-transpose buffer (64 x 66)

    int bid = blockIdx.x;
    int mt  = bid & 15;            // oh0 = 2*mt
    int b   = (bid >> 4) & 7;
    int ksp = bid >> 7;            // 16 ic per split

    int tid = threadIdx.x;
    int l   = tid & 63;
    int wv  = tid >> 6;            // 0..3
    int wm  = wv >> 1;             // output row oh0 + wm
    int wn  = wv & 1;              // oc base = wn*32
    int lc  = l & 15;
    int lg  = l >> 4;              // 0..3

    // ---- D-layout probe: A[m][k] = m, B = delta(k==0,n==0) => D[m][0] = m.
    double ap = (double)lc;
    double bp = (l == 0) ? 1.0 : 0.0;
    f64x4 dp = {0., 0., 0., 0.};
    dp = __builtin_amdgcn_mfma_f64_16x16x4f64(ap, bp, dp, 0, 0, 0);
    int row0[4];
    #pragma unroll
    for (int r = 0; r < 4; ++r)
        row0[r] = ((int)__shfl(dp[r], (l & 0x30), 64)) & 15;

    // ---- stage weights: swt[((khw*4+icb)*64 + n)*4 + g] = w1[n][ksp*16 + icb*4 + g][khw]
    for (int i = tid; i < 9216; i += 256) {
        int g   = i & 3;
        int n   = (i >> 2) & 63;
        int kic = i >> 8;           // khw*4 + icb
        int khw = kic >> 2;
        int icb = kic & 3;
        swt[i] = w1[(n * 128 + ksp * 16 + icb * 4 + g) * 9 + khw];
    }
    __syncthreads();

    f64x4 d00 = {0., 0., 0., 0.}, d01 = {0., 0., 0., 0.};
    f64x4 d10 = {0., 0., 0., 0.}, d11 = {0., 0., 0., 0.};

    // A addressing: channel = ksp*16 + icb*4 + lg
    const float* cb = in + (size_t)(b * 128 + ksp * 16 + lg) * 4096;
    int r0 = 4 * mt + 2 * wm - 1;                       // ih for kh==0 (>= -1)
    const float* pbase = cb + (ptrdiff_t)(r0 * 64 + 2 * lc - 1);
    bool c0ok = (lc != 0);

    // B per-lane base: n = wn*32 + lc (+16 for b1), k-slot = lg
    const float* pB = swt + (wn * 32 + lc) * 4 + lg;

    // A staging: [icb*3 + c] for c = kw offset 0..2; double-buffered across kh
    float a0A[12], a1A[12], a0B[12], a1B[12];

#define LOAD_KH(KH, A0, A1)                                                   \
    {                                                                         \
        const bool rowok = ((KH) > 0) || (r0 >= 0);                           \
        _Pragma("unroll")                                                     \
        for (int icb = 0; icb < 4; ++icb) {                                   \
            _Pragma("unroll")                                                 \
            for (int c = 0; c < 3; ++c) {                                     \
                const int off = icb * 16384 + (KH) * 64 + c;                  \
                bool ok0 = rowok && ((c > 0) || c0ok);                        \
                const float* q0 = ok0 ? (pbase + off) : cb;                   \
                float f0 = *q0;                                               \
                A0[icb * 3 + c] = ok0 ? f0 : 0.f;                             \
                const float* q1 = rowok ? (pbase + off + 32) : cb;            \
                float f1 = *q1;                                               \
                A1[icb * 3 + c] = rowok ? f1 : 0.f;                           \
            }                                                                 \
        }                                                                     \
    }

#define MFMA_KH(KH, A0, A1)                                                   \
    {                                                                         \
        _Pragma("unroll")                                                     \
        for (int kw = 0; kw < 3; ++kw) {                                      \
            const int khw = (KH) * 3 + kw;                                    \
            _Pragma("unroll")                                                 \
            for (int icb = 0; icb < 4; ++icb) {                               \
                double a0 = (double)A0[icb * 3 + kw];                         \
                double a1 = (double)A1[icb * 3 + kw];                         \
                const int offB = (khw * 4 + icb) * 256;                       \
                double b0 = (double)pB[offB];                                 \
                double b1 = (double)pB[offB + 64];                            \
                d00 = __builtin_amdgcn_mfma_f64_16x16x4f64(a0, b0, d00, 0, 0, 0); \
                d01 = __builtin_amdgcn_mfma_f64_16x16x4f64(a0, b1, d01, 0, 0, 0); \
                d10 = __builtin_amdgcn_mfma_f64_16x16x4f64(a1, b0, d10, 0, 0, 0); \
                d11 = __builtin_amdgcn_mfma_f64_16x16x4f64(a1, b1, d11, 0, 0, 0); \
            }                                                                 \
        }                                                                     \
    }

    LOAD_KH(0, a0A, a1A);          // kh 0 -> buf A
    LOAD_KH(1, a0B, a1B);          // kh 1 -> buf B (in flight during kh 0 MFMAs)
    MFMA_KH(0, a0A, a1A);
    LOAD_KH(2, a0A, a1A);          // kh 2 -> buf A (in flight during kh 1 MFMAs)
    MFMA_KH(1, a0B, a1B);
    MFMA_KH(2, a0A, a1A);

#undef LOAD_KH
#undef MFMA_KH

    __syncthreads();   // weights no longer needed; reuse swt as transpose buffer
    float* so = swt;   // 64 oc x 66 = 4224 floats < 9216 (stride 66: conflict <= 2-way)
    #pragma unroll
    for (int mi = 0; mi < 2; ++mi) {
        f64x4 v0 = mi ? d10 : d00;   // ni = 0
        f64x4 v1 = mi ? d11 : d01;   // ni = 1
        #pragma unroll
        for (int r = 0; r < 4; ++r) {
            int m   = wm * 32 + mi * 16 + row0[r];
            int oc0 = wn * 32 + lc;
            so[oc0 * 66 + m]        = (float)v0[r];
            so[(oc0 + 16) * 66 + m] = (float)v1[r];
        }
    }
    __syncthreads();
    int oh0 = 2 * mt;
    for (int i = tid; i < 4096; i += 256) {
        int oc = i >> 6;
        int m  = i & 63;
        part[(size_t)ksp * 524288 +
             ((b * 64 + oc) * 32 + oh0 + (m >> 5)) * 32 + (m & 31)] = so[oc * 66 + m];
    }
}

// ============ conv2 partial, FUSED with conv1-combine (sum 8 partials + BN1 + ReLU) =========
// grid 512 = isp(16: 4 ic) x b(8) x ocg(4); block 256 = full 16x16 spatial
__global__ __launch_bounds__(256) void conv2_partial_kernel(
    const float* __restrict__ part1,
    const float* __restrict__ g1, const float* __restrict__ be1,
    const float* __restrict__ mn1, const float* __restrict__ vr1,
    const float* __restrict__ w,
    float* __restrict__ part)
{
    __shared__ float tin[4][33][36];
    __shared__ float twt[4][9][8];
    __shared__ double sinv[4], ssh[4];

    int bid = blockIdx.x;
    int ocg = bid & 3;
    int b   = (bid >> 2) & 7;
    int isp = bid >> 5;

    int tid = threadIdx.x;
    int ow  = tid & 15;
    int oh  = tid >> 4;

    if (tid < 4) {
        int ch = isp * 4 + tid;
        double inv = (double)g1[ch] / sqrt((double)vr1[ch] + BN_EPS);
        sinv[tid] = inv;
        ssh[tid]  = (double)be1[ch] - (double)mn1[ch] * inv;
    }
    __syncthreads();

    for (int lin = tid; lin < 4 * 33 * 34; lin += 256) {
        int c   = lin % 34;
        int t2  = lin / 34;
        int rr  = t2 % 33;
        int icc = t2 / 33;
        int ih  = rr - 1;
        int iw  = c - 1;
        float v = 0.f;
        if ((unsigned)ih < 32u && (unsigned)iw < 32u) {
            int ch  = isp * 4 + icc;
            int idx = ((b * 64 + ch) * 32 + ih) * 32 + iw;
            double s = 0.0;
            #pragma unroll
            for (int p = 0; p < 8; ++p) s += (double)part1[idx + p * 524288];
            double o = s * sinv[icc] + ssh[icc];
            v = fmaxf((float)o, 0.f);
        }
        tin[icc][rr][c] = v;
    }
    for (int i = tid; i < 288; i += 256) {
        int j   = i & 7;
        int k   = (i >> 3) % 9;
        int icc = i / 72;
        twt[icc][k][j] = w[(ocg * 8 + j) * 576 + (isp * 4 + icc) * 9 + k];
    }
    __syncthreads();

    double acc[8];
    #pragma unroll
    for (int j = 0; j < 8; ++j) acc[j] = 0.0;

    for (int icc = 0; icc < 4; ++icc) {
        double xv[9];
        #pragma unroll
        for (int kh = 0; kh < 3; ++kh)
            #pragma unroll
            for (int kw = 0; kw < 3; ++kw)
                xv[kh * 3 + kw] = (double)tin[icc][2 * oh + kh][2 * ow + kw];
        #pragma unroll
        for (int k = 0; k < 9; ++k) {
            float4 wa = *(const float4*)&twt[icc][k][0];
            float4 wb = *(const float4*)&twt[icc][k][4];
            acc[0] = fma(xv[k], (double)wa.x, acc[0]);
            acc[1] = fma(xv[k], (double)wa.y, acc[1]);
            acc[2] = fma(xv[k], (double)wa.z, acc[2]);
            acc[3] = fma(xv[k], (double)wa.w, acc[3]);
            acc[4] = fma(xv[k], (double)wb.x, acc[4]);
            acc[5] = fma(xv[k], (double)wb.y, acc[5]);
            acc[6] = fma(xv[k], (double)wb.z, acc[6]);
            acc[7] = fma(xv[k], (double)wb.w, acc[7]);
        }
    }
    int obase = ((b * 32 + ocg * 8) * 16 + oh) * 16 + ow;
    #pragma unroll
    for (int j = 0; j < 8; ++j)
        part[isp * 65536 + obase + j * 256] = (float)acc[j];
}

// ============ conv2 combine + BN + ReLU + spatial mean -> ybar[256] ============
__global__ __launch_bounds__(256) void conv2_combine_ybar_kernel(
    const float* __restrict__ part,
    const float* __restrict__ g, const float* __restrict__ be,
    const float* __restrict__ mn, const float* __restrict__ vr,
    double* __restrict__ ybar)
{
    __shared__ double sm[4];
    int j  = blockIdx.x;             // j = b*32 + oc
    int oc = j & 31;
    int t  = threadIdx.x;
    int idx = j * 256 + t;
    double s = 0.0;
    #pragma unroll
    for (int p = 0; p < 16; ++p) s += (double)part[idx + p * 65536];
    double inv = (double)g[oc] / sqrt((double)vr[oc] + BN_EPS);
    double o = s * inv + ((double)be[oc] - (double)mn[oc] * inv);
    double v = fmax(o, 0.0);
    #pragma unroll
    for (int off = 32; off > 0; off >>= 1) v += __shfl_down(v, off, 64);
    if ((t & 63) == 0) sm[t >> 6] = v;
    __syncthreads();
    if (t == 0) ybar[j] = (sm[0] + sm[1] + sm[2] + sm[3]) * (1.0 / 256.0);
}

// ============ centers: conv3(1x1)+BN folded with the spatial mean, fp64 ============
__global__ __launch_bounds__(64) void centers_kernel(
    const double* __restrict__ ybar, const float* __restrict__ w3,
    const float* __restrict__ g, const float* __restrict__ be,
    const float* __restrict__ mn, const float* __restrict__ vr,
    double* __restrict__ cen_ws, float* __restrict__ cen_out)
{
    int t = threadIdx.x;
    if (t < 48) {
        int b = t / 6;
        int k = t % 6;
        double acc = 0.0;
        for (int ic = 0; ic < 32; ++ic) acc = fma((double)w3[k * 32 + ic], ybar[b * 32 + ic], acc);
        double inv = (double)g[k] / sqrt((double)vr[k] + BN_EPS);
        double c = acc * inv + ((double)be[k] - (double)mn[k] * inv);
        cen_ws[t]  = c;
        cen_out[t] = (float)c;
    }
}

// ============ quantization: fp64 dist/argmin, fp32 softmax; float4 I/O ============
__global__ __launch_bounds__(256) void quant_kernel(
    const float* __restrict__ x, const double* __restrict__ centers,
    float* __restrict__ qbar, float* __restrict__ qsoft,
    float* __restrict__ qhard, float* __restrict__ sym)
{
    int vid = blockIdx.x * 256 + threadIdx.x;   // float4 index; 2^17 vecs per batch
    int b = vid >> 17;

    double c[6];
    float cf[6];
    #pragma unroll
    for (int k = 0; k < 6; ++k) { c[k] = centers[b * 6 + k]; cf[k] = (float)c[k]; }

    float4 xv = ((const float4*)x)[vid];
    float xs[4] = {xv.x, xv.y, xv.z, xv.w};
    float r_bar[4], r_soft[4], r_hard[4], r_sym[4];

    #pragma unroll
    for (int i = 0; i < 4; ++i) {
        double xx = (double)xs[i];
        double d[6];
        double dmin = 1e300;
        int amin = 0;
        #pragma unroll
        for (int k = 0; k < 6; ++k) {
            double t = xx - c[k];
            d[k] = t * t;
            if (d[k] < dmin) { dmin = d[k]; amin = k; }
        }
        float se = 0.f, sw = 0.f;
        #pragma unroll
        for (int k = 0; k < 6; ++k) {
            float e = __expf(SIGMA * (float)(dmin - d[k]));
            se += e;
            sw += e * cf[k];
        }
        float qs = sw / se;
        float qh = cf[amin];
        r_soft[i] = qs;
        r_hard[i] = qh;
        r_bar[i]  = qh;
        r_sym[i]  = (float)amin;
    }

    ((float4*)qbar)[vid]  = make_float4(r_bar[0],  r_bar[1],  r_bar[2],  r_bar[3]);
    ((float4*)qsoft)[vid] = make_float4(r_soft[0], r_soft[1], r_soft[2], r_soft[3]);
    ((float4*)qhard)[vid] = make_float4(r_hard[0], r_hard[1], r_hard[2], r_hard[3]);
    ((float4*)sym)[vid]   = make_float4(r_sym[0],  r_sym[1],  r_sym[2],  r_sym[3]);
}

extern "C" void kernel_launch(void* const* d_in, const int* in_sizes, int n_in,
                              void* d_out, int out_size, void* d_ws, size_t ws_size,
                              hipStream_t stream) {
    const float* x  = (const float*)d_in[0];
    const float* cf = (const float*)d_in[1];
    const float* w1 = (const float*)d_in[2];
    const float* g1 = (const float*)d_in[3];
    const float* b1 = (const float*)d_in[4];
    const float* m1 = (const float*)d_in[5];
    const float* v1 = (const float*)d_in[6];
    const float* w2 = (const float*)d_in[7];
    const float* g2 = (const float*)d_in[8];
    const float* b2 = (const float*)d_in[9];
    const float* m2 = (const float*)d_in[10];
    const float* v2 = (const float*)d_in[11];
    const float* w3 = (const float*)d_in[12];
    const float* g3 = (const float*)d_in[13];
    const float* b3 = (const float*)d_in[14];
    const float* m3 = (const float*)d_in[15];
    const float* v3 = (const float*)d_in[16];

    const int NELEM = 8 * 128 * 64 * 64;      // 4,194,304
    float* out   = (float*)d_out;
    float* qbar  = out;
    float* qsoft = out + (size_t)NELEM;
    float* qhard = out + (size_t)2 * NELEM;
    float* sym   = out + (size_t)3 * NELEM;
    float* cen_o = out + (size_t)4 * NELEM;

    char* ws = (char*)d_ws;
    float*  part1 = (float*)(ws);                        // 8 x 524288 f32 = 16 MB
    float*  part2 = (float*)(ws + 16777216);             // 16 x 65536 f32 = 4 MB
    double* yb    = (double*)(ws + 20971520);            // 256 f64
    double* cen   = (double*)(ws + 20973568);            // 48 f64   (~21 MB total)

    conv1_mfma_kernel<<<1024, 256, 0, stream>>>(cf, w1, part1);
    conv2_partial_kernel<<<512, 256, 0, stream>>>(part1, g1, b1, m1, v1, w2, part2);
    conv2_combine_ybar_kernel<<<256, 256, 0, stream>>>(part2, g2, b2, m2, v2, yb);
    centers_kernel<<<1, 64, 0, stream>>>(yb, w3, g3, b3, m3, v3, cen, cen_o);
    quant_kernel<<<NELEM / 4 / 256, 256, 0, stream>>>(x, cen, qbar, qsoft, qhard, sym);
}